// Round 3
// baseline (3256.001 us; speedup 1.0000x reference)
//
#include <hip/hip_runtime.h>
#include <math.h>

// Problem dims (fixed by reference)
#define SEQ    128
#define BATCH  64
#define HD     1024
#define NG     4096
#define TOUT   32
#define NE     65536      // BATCH*HD (also words per h slot / pairs per y slot)
#define CHS    32         // encode steps per chunk
#define MCH    2048       // rows per gemm chunk = CHS*BATCH
#define NHSLOT 4          // rotating tagged h slots (skew within group <= 1)
#define NYSLOT 4          // rotating tagged y slots

typedef __attribute__((ext_vector_type(8))) short    short8;
typedef __attribute__((ext_vector_type(4))) float    f32x4;
typedef __attribute__((ext_vector_type(4))) _Float16 f16x4;

#define MFMA16(a,b,c) __builtin_amdgcn_mfma_f32_16x16x32_bf16((a),(b),(c),0,0,0)

__device__ __forceinline__ ushort bf16_rne(float x) {
    union { float f; unsigned u; } v; v.f = x;
    unsigned r = v.u + 0x7FFF + ((v.u >> 16) & 1);
    return (ushort)(r >> 16);
}

// agent-scope (device-coherent, L2-bypassing) accesses — the dataflow fabric
__device__ __forceinline__ unsigned long long aload64(const void* p) {
    return __hip_atomic_load((const unsigned long long*)p, __ATOMIC_RELAXED,
                             __HIP_MEMORY_SCOPE_AGENT);
}
__device__ __forceinline__ void astore32(void* p, unsigned v) {
    __hip_atomic_store((unsigned*)p, v, __ATOMIC_RELAXED, __HIP_MEMORY_SCOPE_AGENT);
}
__device__ __forceinline__ void astore64(void* p, unsigned long long v) {
    __hip_atomic_store((unsigned long long*)p, v, __ATOMIC_RELAXED,
                       __HIP_MEMORY_SCOPE_AGENT);
}

// ---------------------------------------------------------------------------
// fp32 -> bf16 (RNE), 4 elems/thread; n % 1024 == 0
// ---------------------------------------------------------------------------
__global__ __launch_bounds__(256) void cvt_bf16(
    const float* __restrict__ src, ushort* __restrict__ dst, int n)
{
    int i = (blockIdx.x * 256 + threadIdx.x) * 4;
    if (i < n) {
        float4 v = *(const float4*)(src + i);
        ushort4 o;
        o.x = bf16_rne(v.x); o.y = bf16_rne(v.y);
        o.z = bf16_rne(v.z); o.w = bf16_rne(v.w);
        *(ushort4*)(dst + i) = o;
    }
}

// prep: h0 -> tagged slot 0 (tag=0); tag-clear h slots 1..3 and all y slots;
// cbuf = c0. Runs every invocation (graph-replay safe, no host state).
__global__ __launch_bounds__(256) void prep(
    const float* __restrict__ h0, const float* __restrict__ c0,
    unsigned* __restrict__ Htag, unsigned long long* __restrict__ Ypair,
    float* __restrict__ cbuf)
{
    int i = blockIdx.x * 256 + threadIdx.x;     // 65536 threads
    astore32(Htag + i, ((unsigned)bf16_rne(h0[i]) << 16) | 0u);
    astore32(Htag + NE + i,     0xFFFFFFFFu);   // tag 0xFFFF never matches t<=191
    astore32(Htag + 2 * NE + i, 0xFFFFFFFFu);
    astore32(Htag + 3 * NE + i, 0xFFFFFFFFu);
    #pragma unroll
    for (int s = 0; s < NYSLOT; s++)
        astore32((unsigned*)(Ypair + (size_t)s * NE + i) + 1, 0xFFFFFFFFu);
    cbuf[i] = c0[i];
}

// ---------------------------------------------------------------------------
// Chunk GEMM: XgT[gcol][m] = sum_k A[m][k]*Wih[gcol][k], A bf16 [2048][1024],
// out fp16 transposed (m-pitch 2048). grid (4096/128, 2048/128) = (32,16).
// ---------------------------------------------------------------------------
__global__ __launch_bounds__(256) void gemm_xgt(
    const ushort* __restrict__ A, const ushort* __restrict__ Wih,
    _Float16* __restrict__ XgT)
{
    const int wave = threadIdx.x >> 6, lane = threadIdx.x & 63;
    const int l15 = lane & 15, q8 = (lane >> 4) * 8, r0 = (lane >> 4) * 4;
    const int wr = wave >> 1, wc = wave & 1;
    const int m0 = blockIdx.y * 128 + wr * 64;
    const int n0 = blockIdx.x * 128 + wc * 64;

    const ushort* ap[4];
    const ushort* bp[4];
    #pragma unroll
    for (int f = 0; f < 4; f++) {
        ap[f] = A   + (size_t)(m0 + f * 16 + l15) * 1024 + q8;
        bp[f] = Wih + (size_t)(n0 + f * 16 + l15) * 1024 + q8;
    }

    f32x4 acc[4][4];
    #pragma unroll
    for (int f = 0; f < 4; f++)
        #pragma unroll
        for (int g = 0; g < 4; g++)
            acc[f][g] = (f32x4){0.f, 0.f, 0.f, 0.f};

    for (int kk = 0; kk < 1024; kk += 32) {
        short8 a[4], b[4];
        #pragma unroll
        for (int f = 0; f < 4; f++) {
            a[f] = *(const short8*)(ap[f] + kk);
            b[f] = *(const short8*)(bp[f] + kk);
        }
        #pragma unroll
        for (int f = 0; f < 4; f++)
            #pragma unroll
            for (int g = 0; g < 4; g++)
                acc[f][g] = MFMA16(a[f], b[g], acc[f][g]);
    }

    #pragma unroll
    for (int f = 0; f < 4; f++) {
        const int mbase = m0 + f * 16 + r0;
        #pragma unroll
        for (int g = 0; g < 4; g++) {
            const int gcol = n0 + g * 16 + l15;
            *(f16x4*)(XgT + (size_t)gcol * MCH + mbase) =
                __builtin_convertvector(acc[f][g], f16x4);
        }
    }
}

// ---------------------------------------------------------------------------
// Persistent cooperative LSTM segment — BARRIER-FREE dataflow design.
// h exchange: u32 word per element = (bf16<<16)|step_tag, 4 rotating slots.
// y exchange: u64 pair = (f32 bits)|(tag<<32),            4 rotating slots.
// Producers fire-and-forget agent stores; consumers poll the tagged data
// directly (the poll IS the data load; ~1.5 L3 RTs per hop vs ~4 for the
// drain->atomic->poll->load barrier chain). Skew within a group is <=1 step
// by induction, so 4 slots suffice; tags disambiguate slot generations.
// Groups (bg) touch disjoint rows of each slot -> fully independent.
// ---------------------------------------------------------------------------
__global__ __launch_bounds__(256, 1) void lstm_coop(
    const ushort* __restrict__ Wih, const ushort* __restrict__ Whh,
    const ushort* __restrict__ Wout, const _Float16* __restrict__ XgT,
    unsigned* __restrict__ Htag, unsigned long long* __restrict__ Ypair,
    const float* __restrict__ b_ih, const float* __restrict__ b_hh,
    const float* __restrict__ b_out, float* __restrict__ cbuf,
    float* __restrict__ out, int t0, int nsteps, int dodec)
{
    __shared__ ushort xs[16 * 1032];   // decode: bf16(y - lse) tile
    __shared__ ushort hs[16 * 1032];   // h tile (persists proj -> next cell)
    __shared__ float  ys[16 * 1028];   // f32 y scratch (spill-free softlse)
    __shared__ float  gbuf[1088];

    const int blk  = blockIdx.x;
    const int bg   = blk >> 6, ug = blk & 63;
    const int tid  = threadIdx.x;
    const int wave = tid >> 6, lane = tid & 63;
    const int l15  = lane & 15, q8 = (lane >> 4) * 8, r0 = (lane >> 4) * 4;
    const int b    = tid >> 4, u = tid & 15;

    const int gi = ug * 16 + u;
    const float bs0 = b_ih[gi]        + b_hh[gi];
    const float bs1 = b_ih[1024 + gi] + b_hh[1024 + gi];
    const float bs2 = b_ih[2048 + gi] + b_hh[2048 + gi];
    const float bs3 = b_ih[3072 + gi] + b_hh[3072 + gi];
    const int cidx = ((bg * 16 + b) << 10) + gi;   // [row][unit] element index
    float c_reg = cbuf[cidx];

    const ushort* wip = Wih + (((size_t)(wave * 1024 + ug * 16 + l15)) << 10) + q8;
    const ushort* whp = Whh + (((size_t)(wave * 1024 + ug * 16 + l15)) << 10) + q8;
    const ushort* wop = Wout + (((size_t)(ug * 16 + l15)) << 10) + wave * 256 + q8;
    const _Float16* xgp = XgT + (size_t)(wave * 1024 + ug * 16 + l15) * MCH
                              + bg * 16 + r0;
    const ushort* f0 = xs + l15 * 1032 + q8;
    const ushort* f1 = hs + l15 * 1032 + q8;

    // poll-h geometry: thread covers row tid>>4 of the group tile,
    // 64 consecutive units starting at (tid&15)*64  -> 32 tagged u64 reads.
    const int prow = tid >> 4;
    const int pcol = (tid & 15) * 64;
    const size_t hoff = (size_t)(bg * 16 + prow) * 1024 + pcol;

    auto poll_h = [&](int slot, unsigned tag) {
        const unsigned* basep = Htag + (size_t)slot * NE + hoff;
        ushort* dst = hs + prow * 1032 + pcol;
        const unsigned long long want =
            (unsigned long long)tag | ((unsigned long long)tag << 32);
        unsigned done = 0;
        for (;;) {
            #pragma unroll
            for (int k = 0; k < 32; k++) {
                if (!((done >> k) & 1u)) {
                    unsigned long long q = aload64(basep + 2 * k);
                    if ((q & 0x0000FFFF0000FFFFull) == want) {
                        *(unsigned*)(dst + 2 * k) =
                            (unsigned)((q >> 16) & 0xFFFFull)
                          | ((unsigned)(q >> 48) << 16);
                        done |= 1u << k;
                    }
                }
            }
            if (__syncthreads_and((int)(done == 0xFFFFFFFFu))) break;
            __builtin_amdgcn_s_sleep(4);
        }
    };

    auto gwrite = [&](f32x4 acc) {
        #pragma unroll
        for (int r = 0; r < 4; r++)
            gbuf[(r0 + r) * 68 + wave * 16 + l15] = acc[r];
    };

    auto pointwise = [&](int pslot, unsigned ptag, bool fin) {
        float ig = gbuf[b * 68 + u]      + bs0;
        float fg = gbuf[b * 68 + 16 + u] + bs1;
        float gg = gbuf[b * 68 + 32 + u] + bs2;
        float og = gbuf[b * 68 + 48 + u] + bs3;
        float si = 1.f / (1.f + expf(-ig));
        float sf = 1.f / (1.f + expf(-fg));
        float so = 1.f / (1.f + expf(-og));
        float tg = tanhf(gg);
        float cn = sf * c_reg + si * tg;
        c_reg = cn;
        float hn = so * tanhf(cn);
        astore32(Htag + (size_t)pslot * NE + (size_t)cidx,
                 ((unsigned)bf16_rne(hn) << 16) | ptag);
        if (fin) {
            out[(size_t)TOUT * NE + cidx]       = hn;
            out[(size_t)(TOUT + 1) * NE + cidx] = cn;
        }
    };

    auto proj_step = [&](int hslot, unsigned htag, int yslot, unsigned ytag) {
        poll_h(hslot, htag);                 // hs <- h (persists to next cell)
        const ushort* hpp = hs + l15 * 1032 + wave * 256 + q8;
        f32x4 ac = {0.f, 0.f, 0.f, 0.f};
        #pragma unroll
        for (int kk = 0; kk < 256; kk += 32)
            ac = MFMA16(*(const short8*)(hpp + kk), *(const short8*)(wop + kk), ac);
        #pragma unroll
        for (int r = 0; r < 4; r++)
            gbuf[wave * 256 + (r0 + r) * 16 + l15] = ac[r];
        __syncthreads();
        float vv = gbuf[b * 16 + u] + gbuf[256 + b * 16 + u]
                 + gbuf[512 + b * 16 + u] + gbuf[768 + b * 16 + u]
                 + b_out[ug * 16 + u];
        astore64(Ypair + (size_t)yslot * NE + (size_t)(bg * 16 + b) * 1024
                       + ug * 16 + u,
                 (unsigned long long)__float_as_uint(vv)
               | ((unsigned long long)ytag << 32));
    };

    // Distributed log-softmax with tagged-y polling. Thread (b,u) owns row
    // bg*16+b, pairs {u*4 + s*64 + 0..3}; values stream to LDS scratch ys.
    auto softlse = [&](int yslot, unsigned ytag, float* __restrict__ outp,
                       bool fill_xs) {
        const unsigned long long* yb =
            Ypair + (size_t)yslot * NE + (size_t)(bg * 16 + b) * 1024 + u * 4;
        float* yscr = ys + b * 1028 + u * 4;
        unsigned done = 0;
        for (;;) {
            #pragma unroll
            for (int s2 = 0; s2 < 16; s2++) {
                if (!((done >> s2) & 1u)) {
                    unsigned long long q0 = aload64(yb + s2 * 64 + 0);
                    unsigned long long q1 = aload64(yb + s2 * 64 + 1);
                    unsigned long long q2 = aload64(yb + s2 * 64 + 2);
                    unsigned long long q3 = aload64(yb + s2 * 64 + 3);
                    if ((unsigned)(q0 >> 32) == ytag && (unsigned)(q1 >> 32) == ytag &&
                        (unsigned)(q2 >> 32) == ytag && (unsigned)(q3 >> 32) == ytag) {
                        yscr[s2 * 64 + 0] = __uint_as_float((unsigned)q0);
                        yscr[s2 * 64 + 1] = __uint_as_float((unsigned)q1);
                        yscr[s2 * 64 + 2] = __uint_as_float((unsigned)q2);
                        yscr[s2 * 64 + 3] = __uint_as_float((unsigned)q3);
                        done |= 1u << s2;
                    }
                }
            }
            if (__syncthreads_and((int)(done == 0xFFFFu))) break;
            __builtin_amdgcn_s_sleep(4);
        }
        float mx = -3.4e38f;
        #pragma unroll
        for (int s2 = 0; s2 < 16; s2++) {
            float4 v = *(const float4*)(yscr + s2 * 64);
            mx = fmaxf(mx, fmaxf(fmaxf(v.x, v.y), fmaxf(v.z, v.w)));
        }
        #pragma unroll
        for (int k = 1; k < 16; k <<= 1)
            mx = fmaxf(mx, __shfl_xor(mx, k, 16));
        float sm = 0.f;
        #pragma unroll
        for (int s2 = 0; s2 < 16; s2++) {
            float4 v = *(const float4*)(yscr + s2 * 64);
            sm += expf(v.x - mx) + expf(v.y - mx)
                + expf(v.z - mx) + expf(v.w - mx);
        }
        #pragma unroll
        for (int k = 1; k < 16; k <<= 1)
            sm += __shfl_xor(sm, k, 16);
        const float lse = mx + logf(sm);
        if ((u >> 2) == (ug & 3)) {        // these lanes hold cols ug*16..+15
            float4 v = *(const float4*)(yscr + (ug >> 2) * 64);
            v.x -= lse; v.y -= lse; v.z -= lse; v.w -= lse;
            *(float4*)(outp + (size_t)(bg * 16 + b) * 1024 + ug * 16 + (u & 3) * 4) = v;
        }
        if (fill_xs) {
            ushort* xrow = &xs[b * 1032 + u * 4];
            #pragma unroll
            for (int s2 = 0; s2 < 16; s2++) {
                float4 v = *(const float4*)(yscr + s2 * 64);
                ushort4 w4;
                w4.x = bf16_rne(v.x - lse); w4.y = bf16_rne(v.y - lse);
                w4.z = bf16_rne(v.z - lse); w4.w = bf16_rne(v.w - lse);
                *(ushort4*)(xrow + s2 * 64) = w4;
            }
        }
    };

    // ================= encode segment: zero barriers =================
    for (int s = 0; s < nsteps; s++) {
        const int t = t0 + s;
        f16x4 xg4 = *(const f16x4*)(xgp + (size_t)s * 64);   // indep of h(t)
        poll_h(t & 3, (unsigned)t);        // detect + load h(t) in one go
        f32x4 a0 = __builtin_convertvector(xg4, f32x4);
        f32x4 a1 = {0.f, 0.f, 0.f, 0.f};
        #pragma unroll 8
        for (int kk = 0; kk < 512; kk += 32)
            a0 = MFMA16(*(const short8*)(f1 + kk), *(const short8*)(whp + kk), a0);
        #pragma unroll 8
        for (int kk = 512; kk < 1024; kk += 32)
            a1 = MFMA16(*(const short8*)(f1 + kk), *(const short8*)(whp + kk), a1);
        gwrite(a0 + a1);
        __syncthreads();
        pointwise((t + 1) & 3, (unsigned)(t + 1), false);   // fire-and-forget
    }

    if (!dodec) {
        cbuf[cidx] = c_reg;   // spill recurrent c for the next segment
        return;
    }

    // ================= out0 =================
    proj_step(SEQ & 3, (unsigned)SEQ, 0, 0u);   // y(0)

    // ================= decode: 31 steps =================
    for (int d = 1; d < TOUT; d++) {
        // ---- cell(d): h-GEMM first (hs staged by proj), then poll y ----
        f32x4 a0 = {0.f,0.f,0.f,0.f}, a1 = {0.f,0.f,0.f,0.f};
        #pragma unroll 8
        for (int kk = 0; kk < 512; kk += 32)
            a0 = MFMA16(*(const short8*)(f1 + kk), *(const short8*)(whp + kk), a0);
        #pragma unroll 8
        for (int kk = 512; kk < 1024; kk += 32)
            a1 = MFMA16(*(const short8*)(f1 + kk), *(const short8*)(whp + kk), a1);
        softlse((d - 1) & 3, (unsigned)(d - 1), out + (size_t)(d - 1) * NE, true);
        __syncthreads();                   // xs ready
        #pragma unroll 8
        for (int kk = 0; kk < 512; kk += 32)
            a0 = MFMA16(*(const short8*)(f0 + kk), *(const short8*)(wip + kk), a0);
        #pragma unroll 8
        for (int kk = 512; kk < 1024; kk += 32)
            a1 = MFMA16(*(const short8*)(f0 + kk), *(const short8*)(wip + kk), a1);
        gwrite(a0 + a1);
        __syncthreads();
        pointwise((SEQ + d) & 3, (unsigned)(SEQ + d), d == TOUT - 1);

        // ---- proj(d): poll h(SEQ+d), project, publish y(d) ----
        proj_step((SEQ + d) & 3, (unsigned)(SEQ + d), d & 3, (unsigned)d);
    }

    // ================= epilogue: out[31] = y(31) - lse =================
    softlse((TOUT - 1) & 3, (unsigned)(TOUT - 1),
            out + (size_t)(TOUT - 1) * NE, false);
}

// ---------------------------------------------------------------------------
extern "C" void kernel_launch(void* const* d_in, const int* in_sizes, int n_in,
                              void* d_out, int out_size, void* d_ws, size_t ws_size,
                              hipStream_t stream)
{
    const float* input = (const float*)d_in[0];   // [128,64,1024]
    const float* h0    = (const float*)d_in[1];
    const float* c0    = (const float*)d_in[2];
    const float* W_ih  = (const float*)d_in[3];   // [4096,1024]
    const float* W_hh  = (const float*)d_in[4];
    const float* b_ih  = (const float*)d_in[5];
    const float* b_hh  = (const float*)d_in[6];
    const float* W_out = (const float*)d_in[7];   // [1024,1024]
    const float* b_out = (const float*)d_in[8];
    float* out = (float*)d_out;                   // [32,64,1024] + h + c

    char* w = (char*)d_ws;                                        // bytes
    ushort*             Whh_bf = (ushort*)             (w + 0);          //  8,388,608
    ushort*             Wih_bf = (ushort*)             (w + 8388608);    //  8,388,608
    ushort*             Wout_bf= (ushort*)             (w + 16777216);   //  2,097,152
    _Float16*           XgT    = (_Float16*)           (w + 18874368);   // 16,777,216
    ushort*             Xbc    = (ushort*)             (w + 35651584);   //  4,194,304
    unsigned*           Htag   = (unsigned*)           (w + 39845888);   //  1,048,576
    unsigned long long* Ypair  = (unsigned long long*) (w + 40894464);   //  2,097,152
    float*              cbuf   = (float*)              (w + 42991616);   //    262,144
    // total ~43.3 MB (proven budget: 86.7 MB)

    cvt_bf16<<<dim3(4096), dim3(256), 0, stream>>>(W_ih,  Wih_bf,  NG * HD);
    cvt_bf16<<<dim3(4096), dim3(256), 0, stream>>>(W_hh,  Whh_bf,  NG * HD);
    cvt_bf16<<<dim3(1024), dim3(256), 0, stream>>>(W_out, Wout_bf, HD * HD);
    prep<<<dim3(256), dim3(256), 0, stream>>>(h0, c0, Htag, Ypair, cbuf);

    for (int ch = 0; ch < SEQ / CHS; ch++) {
        cvt_bf16<<<dim3(2048), dim3(256), 0, stream>>>(
            input + (size_t)ch * CHS * NE, Xbc, CHS * NE);
        gemm_xgt<<<dim3(32, 16), dim3(256), 0, stream>>>(Xbc, Wih_bf, XgT);

        const ushort* a0 = Wih_bf;  const ushort* a1 = Whh_bf;
        const ushort* a2 = Wout_bf; const _Float16* a3 = XgT;
        unsigned* a4 = Htag; unsigned long long* a5 = Ypair;
        const float* a6 = b_ih; const float* a7 = b_hh; const float* a8 = b_out;
        float* a9 = cbuf; float* a10 = out;
        int t0 = ch * CHS, ns = CHS, dodec = (ch == SEQ / CHS - 1) ? 1 : 0;
        void* args[] = {&a0, &a1, &a2, &a3, &a4, &a5, &a6, &a7,
                        &a8, &a9, &a10, &t0, &ns, &dodec};
        hipLaunchCooperativeKernel((const void*)lstm_coop, dim3(256), dim3(256),
                                   args, 0, stream);
    }
}

// Round 4
// 1522.530 us; speedup vs baseline: 2.1385x; 2.1385x over previous
//
#include <hip/hip_runtime.h>
#include <math.h>

// Problem dims (fixed by reference)
#define SEQ    128
#define BATCH  64
#define HD     1024
#define NG     4096
#define TOUT   32
#define NE     65536      // BATCH*HD
#define CHS    32         // encode steps per chunk
#define MCH    2048       // rows per gemm chunk = CHS*BATCH
#define NHBUF  160        // SEQ + TOUT h buffers (write-once rotation)
#define NBAR   1024       // barrier words (4 counters, 256B apart)

typedef __attribute__((ext_vector_type(8))) short    short8;
typedef __attribute__((ext_vector_type(4))) float    f32x4;
typedef __attribute__((ext_vector_type(4))) _Float16 f16x4;

#define MFMA16(a,b,c) __builtin_amdgcn_mfma_f32_16x16x32_bf16((a),(b),(c),0,0,0)

__device__ __forceinline__ ushort bf16_rne(float x) {
    union { float f; unsigned u; } v; v.f = x;
    unsigned r = v.u + 0x7FFF + ((v.u >> 16) & 1);
    return (ushort)(r >> 16);
}

// device-coherent (agent-scope) store: push to coherence point, no fences
__device__ __forceinline__ void cstore32(void* p, unsigned v) {
    __hip_atomic_store((unsigned*)p, v, __ATOMIC_RELAXED, __HIP_MEMORY_SCOPE_AGENT);
}

// XOR-swizzled element offset into a [rows][1024] bf16 LDS tile.
// 16B granules: granule (col>>3) is XOR'd with (row&7) -> ds_read_b128 of a
// "column" across 16 rows hits 8 distinct 16B slots = 2-way/bank = free.
__device__ __forceinline__ int swz(int row, int col) {
    return (row << 10) + ((((col >> 3) ^ (row & 7)) << 3) | (col & 7));
}

// ---------------------------------------------------------------------------
// fp32 -> bf16 (RNE), 4 elems/thread; n % 1024 == 0
// ---------------------------------------------------------------------------
__global__ __launch_bounds__(256) void cvt_bf16(
    const float* __restrict__ src, ushort* __restrict__ dst, int n)
{
    int i = (blockIdx.x * 256 + threadIdx.x) * 4;
    if (i < n) {
        float4 v = *(const float4*)(src + i);
        ushort4 o;
        o.x = bf16_rne(v.x); o.y = bf16_rne(v.y);
        o.z = bf16_rne(v.z); o.w = bf16_rne(v.w);
        *(ushort4*)(dst + i) = o;
    }
}

// prep: h0 -> bf16 into hbuf(0); cbuf = c0; zero barrier counters.
__global__ __launch_bounds__(256) void prep(
    const float* __restrict__ h0, const float* __restrict__ c0,
    ushort* __restrict__ h0b, float* __restrict__ cbuf, unsigned* __restrict__ bar)
{
    int i = blockIdx.x * 256 + threadIdx.x;
    h0b[i] = bf16_rne(h0[i]);
    cbuf[i] = c0[i];
    if (blockIdx.x == 0)
        for (int k = threadIdx.x; k < NBAR; k += 256) bar[k] = 0u;
}

// ---------------------------------------------------------------------------
// Chunk GEMM: XgT[gcol][m] = sum_k A[m][k]*Wih[gcol][k], A bf16 [2048][1024],
// out fp16 transposed (m-pitch 2048). grid (4096/128, 2048/128) = (32,16).
// ---------------------------------------------------------------------------
__global__ __launch_bounds__(256) void gemm_xgt(
    const ushort* __restrict__ A, const ushort* __restrict__ Wih,
    _Float16* __restrict__ XgT)
{
    const int wave = threadIdx.x >> 6, lane = threadIdx.x & 63;
    const int l15 = lane & 15, q8 = (lane >> 4) * 8, r0 = (lane >> 4) * 4;
    const int wr = wave >> 1, wc = wave & 1;
    const int m0 = blockIdx.y * 128 + wr * 64;
    const int n0 = blockIdx.x * 128 + wc * 64;

    const ushort* ap[4];
    const ushort* bp[4];
    #pragma unroll
    for (int f = 0; f < 4; f++) {
        ap[f] = A   + (size_t)(m0 + f * 16 + l15) * 1024 + q8;
        bp[f] = Wih + (size_t)(n0 + f * 16 + l15) * 1024 + q8;
    }

    f32x4 acc[4][4];
    #pragma unroll
    for (int f = 0; f < 4; f++)
        #pragma unroll
        for (int g = 0; g < 4; g++)
            acc[f][g] = (f32x4){0.f, 0.f, 0.f, 0.f};

    for (int kk = 0; kk < 1024; kk += 32) {
        short8 a[4], b[4];
        #pragma unroll
        for (int f = 0; f < 4; f++) {
            a[f] = *(const short8*)(ap[f] + kk);
            b[f] = *(const short8*)(bp[f] + kk);
        }
        #pragma unroll
        for (int f = 0; f < 4; f++)
            #pragma unroll
            for (int g = 0; g < 4; g++)
                acc[f][g] = MFMA16(a[f], b[g], acc[f][g]);
    }

    #pragma unroll
    for (int f = 0; f < 4; f++) {
        const int mbase = m0 + f * 16 + r0;
        #pragma unroll
        for (int g = 0; g < 4; g++) {
            const int gcol = n0 + g * 16 + l15;
            *(f16x4*)(XgT + (size_t)gcol * MCH + mbase) =
                __builtin_convertvector(acc[f][g], f16x4);
        }
    }
}

// ---------------------------------------------------------------------------
// Flat monotonic group barrier (64 blocks/group) — proven in round 2.
// ---------------------------------------------------------------------------
__device__ __forceinline__ void g_arrive(unsigned* ctr) {
    asm volatile("s_waitcnt vmcnt(0) lgkmcnt(0)" ::: "memory");
    __syncthreads();
    if (threadIdx.x == 0)
        __hip_atomic_fetch_add(ctr, 1u, __ATOMIC_RELAXED, __HIP_MEMORY_SCOPE_AGENT);
}
__device__ __forceinline__ void g_wait(unsigned* ctr, unsigned tgt) {
    if (threadIdx.x == 0) {
        while (__hip_atomic_load(ctr, __ATOMIC_RELAXED, __HIP_MEMORY_SCOPE_AGENT) < tgt)
            __builtin_amdgcn_s_sleep(1);
    }
    __syncthreads();
}

// ---------------------------------------------------------------------------
// Persistent cooperative LSTM segment — WEIGHTS-STATIONARY design.
// Each block parks its 64 Whh gate-rows (4 gates x 16 units) swizzled in LDS
// (131072 B). Per step only h (32 KB/block) moves; cell MFMAs are LDS-fed.
// This removes the per-step 128-256 KB/block weight re-stream that thrashed
// L2 (4-5 MB/XCD/step) and re-fetched ~83 MB/dispatch from HBM (the measured
// latency-bound bottleneck; sync A/B in rounds 0-2 proved barriers are minor).
// Decode: Whh from LDS, Wih/Wout streamed (no LDS room); softlse is 2-pass
// over cached global y (no LDS scratch). gbuf aliases the A-tile (resynced).
// ---------------------------------------------------------------------------
__global__ __launch_bounds__(256, 1) void lstm_coop(
    const ushort* __restrict__ Wih, const ushort* __restrict__ Whh,
    const ushort* __restrict__ Wout, const _Float16* __restrict__ XgT,
    ushort* __restrict__ Hbase, float* __restrict__ Ybase,
    unsigned* __restrict__ bar,
    const float* __restrict__ b_ih, const float* __restrict__ b_hh,
    const float* __restrict__ b_out, float* __restrict__ cbuf,
    float* __restrict__ out, int t0, int nsteps, int dodec, unsigned ep0)
{
    __shared__ ushort WB[64 * 1024];   // 131072 B swizzled Whh slice (resident)
    __shared__ ushort AT[16 * 1024];   //  32768 B swizzled A tile (h, then x)
    float* gbuf = (float*)AT;          // alias: cross-wave gate/proj exchange

    const int blk  = blockIdx.x;
    const int bg   = blk >> 6, ug = blk & 63;
    const int tid  = threadIdx.x;
    const int wave = tid >> 6, lane = tid & 63;
    const int l15  = lane & 15, q8 = (lane >> 4) * 8, r0 = (lane >> 4) * 4;
    const int b    = tid >> 4, u = tid & 15;

    unsigned* ctr = bar + bg * 64;     // 256B apart per group
    unsigned ep = ep0;                 // arrivals so far (monotonic)

    const int gi = ug * 16 + u;
    const float bs0 = b_ih[gi]        + b_hh[gi];
    const float bs1 = b_ih[1024 + gi] + b_hh[1024 + gi];
    const float bs2 = b_ih[2048 + gi] + b_hh[2048 + gi];
    const float bs3 = b_ih[3072 + gi] + b_hh[3072 + gi];
    const int cidx = ((bg * 16 + b) << 10) + gi;
    float c_reg = cbuf[cidx];

    // park Whh slice in LDS (once per launch): rows rr = gate*16 + j
    for (int it = 0; it < 32; it++) {
        int idx = it * 256 + tid;          // granule id, 8192 total
        int row = idx >> 7, g = idx & 127;
        const ushort* src = Whh
            + (((size_t)((row >> 4) * 1024 + ug * 16 + (row & 15))) << 10) + g * 8;
        *(short8*)&WB[(row << 10) + ((g ^ (row & 7)) << 3)] = *(const short8*)src;
    }
    __syncthreads();

    const ushort* wip = Wih + (((size_t)(wave * 1024 + ug * 16 + l15)) << 10) + q8;
    const ushort* wop = Wout + (((size_t)(ug * 16 + l15)) << 10) + wave * 256 + q8;
    const _Float16* xgp = XgT + (size_t)(wave * 1024 + ug * 16 + l15) * MCH
                              + bg * 16 + r0;
    const int wrow = wave * 16 + l15;  // this lane's WB row

    auto hbuf = [&](int t) -> ushort* {
        return Hbase + (size_t)(NHBUF - 1 - t) * NE;
    };

    // stage 16x1024 bf16 global slice -> swizzled AT
    auto stage_swz = [&](const ushort* __restrict__ src) {
        short8 t[8];
        #pragma unroll
        for (int i = 0; i < 8; i++) {
            int idx = i * 256 + tid;
            t[i] = *(const short8*)(src + ((size_t)(idx >> 7) << 10) + (idx & 127) * 8);
        }
        #pragma unroll
        for (int i = 0; i < 8; i++) {
            int idx = i * 256 + tid;
            int row = idx >> 7, g = idx & 127;
            *(short8*)&AT[(row << 10) + ((g ^ (row & 7)) << 3)] = t[i];
        }
    };

    auto gwrite = [&](f32x4 acc) {      // caller must __syncthreads() before
        #pragma unroll
        for (int r = 0; r < 4; r++)
            gbuf[(r0 + r) * 68 + wave * 16 + l15] = acc[r];
    };

    auto pointwise = [&](ushort* hnxt, bool fin) {
        float ig = gbuf[b * 68 + u]      + bs0;
        float fg = gbuf[b * 68 + 16 + u] + bs1;
        float gg = gbuf[b * 68 + 32 + u] + bs2;
        float og = gbuf[b * 68 + 48 + u] + bs3;
        float si = 1.f / (1.f + expf(-ig));
        float sf = 1.f / (1.f + expf(-fg));
        float so = 1.f / (1.f + expf(-og));
        float tg = tanhf(gg);
        float cn = sf * c_reg + si * tg;
        c_reg = cn;
        float hn = so * tanhf(cn);
        ushort hb16 = bf16_rne(hn);
        unsigned hi = (unsigned)(ushort)__shfl_down((int)hb16, 1);
        if ((u & 1) == 0)
            cstore32((void*)(hnxt + cidx), (unsigned)hb16 | (hi << 16));
        if (fin) {
            out[(size_t)TOUT * NE + cidx]       = hn;
            out[(size_t)(TOUT + 1) * NE + cidx] = cn;
        }
    };

    auto proj_step = [&](const ushort* hcur, float* ydst) {
        stage_swz(hcur + ((size_t)(bg * 16) << 10));
        __syncthreads();
        f32x4 ac = {0.f, 0.f, 0.f, 0.f};
        #pragma unroll
        for (int kk = 0; kk < 256; kk += 32)
            ac = MFMA16(*(const short8*)(AT + swz(l15, wave * 256 + q8 + kk)),
                        *(const short8*)(wop + kk), ac);
        __syncthreads();               // all AT reads done (gbuf aliases AT)
        #pragma unroll
        for (int r = 0; r < 4; r++)
            gbuf[wave * 256 + (r0 + r) * 16 + l15] = ac[r];
        __syncthreads();
        float vv = gbuf[b * 16 + u] + gbuf[256 + b * 16 + u]
                 + gbuf[512 + b * 16 + u] + gbuf[768 + b * 16 + u]
                 + b_out[ug * 16 + u];
        cstore32(ydst + (size_t)(bg * 16 + b) * 1024 + ug * 16 + u,
                 __float_as_uint(vv));
    };

    // 2-pass distributed log-softmax over cached global y; optional x-fill
    // into swizzled AT. Thread (b,u) owns row bg*16+b, cols {u*4 + s*64}.
    auto softlse = [&](const float* yb, float* outp, bool fill_at) {
        const float* yrow = yb + (size_t)(bg * 16 + b) * 1024 + u * 4;
        float mx = -3.4e38f;
        #pragma unroll
        for (int s = 0; s < 16; s++) {
            float4 v = *(const float4*)(yrow + s * 64);
            mx = fmaxf(mx, fmaxf(fmaxf(v.x, v.y), fmaxf(v.z, v.w)));
        }
        #pragma unroll
        for (int k = 1; k < 16; k <<= 1)
            mx = fmaxf(mx, __shfl_xor(mx, k, 16));
        float sm = 0.f;
        #pragma unroll
        for (int s = 0; s < 16; s++) {
            float4 v = *(const float4*)(yrow + s * 64);
            sm += expf(v.x - mx) + expf(v.y - mx)
                + expf(v.z - mx) + expf(v.w - mx);
        }
        #pragma unroll
        for (int k = 1; k < 16; k <<= 1)
            sm += __shfl_xor(sm, k, 16);
        const float lse = mx + logf(sm);
        if ((u >> 2) == (ug & 3)) {        // these lanes hold cols ug*16..+15
            float4 v = *(const float4*)(yrow + ((ug >> 2) - (u >> 2)) * 0
                                        + (ug >> 2) * 64);
            v.x -= lse; v.y -= lse; v.z -= lse; v.w -= lse;
            *(float4*)(outp + (size_t)(bg * 16 + b) * 1024 + ug * 16 + (u & 3) * 4) = v;
        }
        if (fill_at) {
            #pragma unroll
            for (int s = 0; s < 16; s++) {
                float4 v = *(const float4*)(yrow + s * 64);
                ushort4 w4;
                w4.x = bf16_rne(v.x - lse); w4.y = bf16_rne(v.y - lse);
                w4.z = bf16_rne(v.z - lse); w4.w = bf16_rne(v.w - lse);
                int col = u * 4 + s * 64;
                *(ushort4*)&AT[swz(b, col)] = w4;
            }
        }
    };

    // ================= encode segment: 1 barrier/step =================
    for (int s = 0; s < nsteps; s++) {
        const int t = t0 + s;
        f16x4 xg4 = *(const f16x4*)(xgp + (size_t)s * 64);   // indep of h(t)
        g_wait(ctr, ep * 64u);             // h(t) visible
        stage_swz(hbuf(t) + ((size_t)(bg * 16) << 10));
        __syncthreads();
        f32x4 a0 = __builtin_convertvector(xg4, f32x4);
        f32x4 a1 = {0.f, 0.f, 0.f, 0.f};
        #pragma unroll 8
        for (int kk = 0; kk < 512; kk += 32)
            a0 = MFMA16(*(const short8*)(AT + swz(l15, kk + q8)),
                        *(const short8*)(WB + swz(wrow, kk + q8)), a0);
        #pragma unroll 8
        for (int kk = 512; kk < 1024; kk += 32)
            a1 = MFMA16(*(const short8*)(AT + swz(l15, kk + q8)),
                        *(const short8*)(WB + swz(wrow, kk + q8)), a1);
        __syncthreads();                   // AT reads done (gbuf aliases AT)
        gwrite(a0 + a1);
        __syncthreads();
        pointwise(hbuf(t + 1), false);
        g_arrive(ctr); ep++;               // publish h(t+1)
    }

    if (!dodec) {
        cbuf[cidx] = c_reg;   // spill recurrent c for the next segment
        return;
    }

    // ================= out0 =================
    g_wait(ctr, ep * 64u);                 // h(SEQ) visible
    proj_step(hbuf(SEQ), Ybase);           // y slot 0
    g_arrive(ctr); ep++;

    // ================= decode: 31 steps, 2 barriers each =================
    for (int d = 1; d < TOUT; d++) {
        // ---- cell(d): h-GEMM (LDS weights) in the y-wait shadow ----
        stage_swz(hbuf(SEQ + d - 1) + ((size_t)(bg * 16) << 10));
        __syncthreads();
        f32x4 a0 = {0.f,0.f,0.f,0.f}, a1 = {0.f,0.f,0.f,0.f};
        #pragma unroll 8
        for (int kk = 0; kk < 512; kk += 32)
            a0 = MFMA16(*(const short8*)(AT + swz(l15, kk + q8)),
                        *(const short8*)(WB + swz(wrow, kk + q8)), a0);
        #pragma unroll 8
        for (int kk = 512; kk < 1024; kk += 32)
            a1 = MFMA16(*(const short8*)(AT + swz(l15, kk + q8)),
                        *(const short8*)(WB + swz(wrow, kk + q8)), a1);
        g_wait(ctr, ep * 64u);             // y(d-1) visible (syncthreads inside)
        softlse(Ybase + (size_t)(d - 1) * NE, out + (size_t)(d - 1) * NE, true);
        __syncthreads();                   // AT now holds x(d-1)
        #pragma unroll 8
        for (int kk = 0; kk < 512; kk += 32)
            a0 = MFMA16(*(const short8*)(AT + swz(l15, kk + q8)),
                        *(const short8*)(wip + kk), a0);
        #pragma unroll 8
        for (int kk = 512; kk < 1024; kk += 32)
            a1 = MFMA16(*(const short8*)(AT + swz(l15, kk + q8)),
                        *(const short8*)(wip + kk), a1);
        __syncthreads();                   // AT reads done (gbuf aliases AT)
        gwrite(a0 + a1);
        __syncthreads();
        pointwise(hbuf(SEQ + d), d == TOUT - 1);
        g_arrive(ctr); ep++;               // publish h(SEQ+d)

        // ---- proj(d) ----
        g_wait(ctr, ep * 64u);             // h(SEQ+d) visible
        proj_step(hbuf(SEQ + d), Ybase + (size_t)d * NE);
        g_arrive(ctr); ep++;               // publish y(d)
    }

    // ================= epilogue: out[31] = y(31) - lse =================
    g_wait(ctr, ep * 64u);                 // y(31) visible
    softlse(Ybase + (size_t)(TOUT - 1) * NE, out + (size_t)(TOUT - 1) * NE, false);
}

// ---------------------------------------------------------------------------
extern "C" void kernel_launch(void* const* d_in, const int* in_sizes, int n_in,
                              void* d_out, int out_size, void* d_ws, size_t ws_size,
                              hipStream_t stream)
{
    const float* input = (const float*)d_in[0];   // [128,64,1024]
    const float* h0    = (const float*)d_in[1];
    const float* c0    = (const float*)d_in[2];
    const float* W_ih  = (const float*)d_in[3];   // [4096,1024]
    const float* W_hh  = (const float*)d_in[4];
    const float* b_ih  = (const float*)d_in[5];
    const float* b_hh  = (const float*)d_in[6];
    const float* W_out = (const float*)d_in[7];   // [1024,1024]
    const float* b_out = (const float*)d_in[8];
    float* out = (float*)d_out;                   // [32,64,1024] + h + c

    char* w = (char*)d_ws;                                    // bytes
    ushort*    Whh_bf = (ushort*)   (w + 0);                  //  8,388,608
    ushort*    Wih_bf = (ushort*)   (w + 8388608);            //  8,388,608
    ushort*    Wout_bf= (ushort*)   (w + 16777216);           //  2,097,152
    _Float16*  XgT    = (_Float16*) (w + 18874368);           // 16,777,216
    ushort*    Xbc    = (ushort*)   (w + 35651584);           //  4,194,304
    ushort*    Hbase  = (ushort*)   (w + 39845888);           // 20,971,520
    float*     Ybase  = (float*)    (w + 60817408);           //  8,388,608 (32 slots)
    float*     cbuf   = (float*)    (w + 69206016);           //    262,144
    unsigned*  bar    = (unsigned*) (w + 69468160);           //      4,096
    // total ~69.5 MB (proven budget: 86.7 MB)

    cvt_bf16<<<dim3(4096), dim3(256), 0, stream>>>(W_ih,  Wih_bf,  NG * HD);
    cvt_bf16<<<dim3(4096), dim3(256), 0, stream>>>(W_hh,  Whh_bf,  NG * HD);
    cvt_bf16<<<dim3(1024), dim3(256), 0, stream>>>(W_out, Wout_bf, HD * HD);
    // hbuf(0) = Hbase + (NHBUF-1)*NE
    prep<<<dim3(256), dim3(256), 0, stream>>>(
        h0, c0, Hbase + (size_t)(NHBUF - 1) * NE, cbuf, bar);

    for (int ch = 0; ch < SEQ / CHS; ch++) {
        cvt_bf16<<<dim3(2048), dim3(256), 0, stream>>>(
            input + (size_t)ch * CHS * NE, Xbc, CHS * NE);
        gemm_xgt<<<dim3(32, 16), dim3(256), 0, stream>>>(Xbc, Wih_bf, XgT);

        const ushort* a0 = Wih_bf;  const ushort* a1 = Whh_bf;
        const ushort* a2 = Wout_bf; const _Float16* a3 = XgT;
        ushort* a4 = Hbase; float* a5 = Ybase; unsigned* a6 = bar;
        const float* a7 = b_ih; const float* a8 = b_hh; const float* a9 = b_out;
        float* a10 = cbuf; float* a11 = out;
        int t0 = ch * CHS, ns = CHS, dodec = (ch == SEQ / CHS - 1) ? 1 : 0;
        unsigned ep0 = (unsigned)(ch * CHS);   // arrivals in prior chunks
        void* args[] = {&a0, &a1, &a2, &a3, &a4, &a5, &a6, &a7,
                        &a8, &a9, &a10, &a11, &t0, &ns, &dodec, &ep0};
        hipLaunchCooperativeKernel((const void*)lstm_coop, dim3(256), dim3(256),
                                   args, 0, stream);
    }
}

// Round 5
// 1413.576 us; speedup vs baseline: 2.3034x; 1.0771x over previous
//
#include <hip/hip_runtime.h>
#include <math.h>

// Problem dims (fixed by reference)
#define SEQ    128
#define BATCH  64
#define HD     1024
#define NG     4096
#define TOUT   32
#define NE     65536      // BATCH*HD
#define CHS    32         // encode steps per chunk
#define MCH    2048       // rows per gemm chunk = CHS*BATCH
#define NHBUF  160        // SEQ + TOUT h buffers (write-once rotation)
#define NBAR   4096       // barrier words: 4 groups x 64 blocks x 16-word stride

typedef __attribute__((ext_vector_type(8))) short    short8;
typedef __attribute__((ext_vector_type(4))) float    f32x4;
typedef __attribute__((ext_vector_type(4))) _Float16 f16x4;

#define MFMA16(a,b,c) __builtin_amdgcn_mfma_f32_16x16x32_bf16((a),(b),(c),0,0,0)

__device__ __forceinline__ ushort bf16_rne(float x) {
    union { float f; unsigned u; } v; v.f = x;
    unsigned r = v.u + 0x7FFF + ((v.u >> 16) & 1);
    return (ushort)(r >> 16);
}

// device-coherent (agent-scope) store: push to coherence point, no fences
__device__ __forceinline__ void cstore32(void* p, unsigned v) {
    __hip_atomic_store((unsigned*)p, v, __ATOMIC_RELAXED, __HIP_MEMORY_SCOPE_AGENT);
}

// XOR-swizzled element offset into a [rows][1024] bf16 LDS tile.
// 16B granules: granule (col>>3) is XOR'd with (row&7) -> ds_read_b128 of a
// "column" across 16 rows hits 8 distinct 16B slots = 2-way/bank = free.
__device__ __forceinline__ int swz(int row, int col) {
    return (row << 10) + ((((col >> 3) ^ (row & 7)) << 3) | (col & 7));
}

// ---------------------------------------------------------------------------
// fp32 -> bf16 (RNE), 4 elems/thread; n % 1024 == 0
// ---------------------------------------------------------------------------
__global__ __launch_bounds__(256) void cvt_bf16(
    const float* __restrict__ src, ushort* __restrict__ dst, int n)
{
    int i = (blockIdx.x * 256 + threadIdx.x) * 4;
    if (i < n) {
        float4 v = *(const float4*)(src + i);
        ushort4 o;
        o.x = bf16_rne(v.x); o.y = bf16_rne(v.y);
        o.z = bf16_rne(v.z); o.w = bf16_rne(v.w);
        *(ushort4*)(dst + i) = o;
    }
}

// prep: h0 -> bf16 into hbuf(0); cbuf = c0; zero barrier words.
__global__ __launch_bounds__(256) void prep(
    const float* __restrict__ h0, const float* __restrict__ c0,
    ushort* __restrict__ h0b, float* __restrict__ cbuf, unsigned* __restrict__ bar)
{
    int i = blockIdx.x * 256 + threadIdx.x;
    h0b[i] = bf16_rne(h0[i]);
    cbuf[i] = c0[i];
    if (blockIdx.x == 0)
        for (int k = threadIdx.x; k < NBAR; k += 256) bar[k] = 0u;
}

// ---------------------------------------------------------------------------
// Chunk GEMM: XgT[gcol][m] = sum_k A[m][k]*Wih[gcol][k], A bf16 [2048][1024],
// out fp16 transposed (m-pitch 2048). grid (4096/128, 2048/128) = (32,16).
// ---------------------------------------------------------------------------
__global__ __launch_bounds__(256) void gemm_xgt(
    const ushort* __restrict__ A, const ushort* __restrict__ Wih,
    _Float16* __restrict__ XgT)
{
    const int wave = threadIdx.x >> 6, lane = threadIdx.x & 63;
    const int l15 = lane & 15, q8 = (lane >> 4) * 8, r0 = (lane >> 4) * 4;
    const int wr = wave >> 1, wc = wave & 1;
    const int m0 = blockIdx.y * 128 + wr * 64;
    const int n0 = blockIdx.x * 128 + wc * 64;

    const ushort* ap[4];
    const ushort* bp[4];
    #pragma unroll
    for (int f = 0; f < 4; f++) {
        ap[f] = A   + (size_t)(m0 + f * 16 + l15) * 1024 + q8;
        bp[f] = Wih + (size_t)(n0 + f * 16 + l15) * 1024 + q8;
    }

    f32x4 acc[4][4];
    #pragma unroll
    for (int f = 0; f < 4; f++)
        #pragma unroll
        for (int g = 0; g < 4; g++)
            acc[f][g] = (f32x4){0.f, 0.f, 0.f, 0.f};

    for (int kk = 0; kk < 1024; kk += 32) {
        short8 a[4], b[4];
        #pragma unroll
        for (int f = 0; f < 4; f++) {
            a[f] = *(const short8*)(ap[f] + kk);
            b[f] = *(const short8*)(bp[f] + kk);
        }
        #pragma unroll
        for (int f = 0; f < 4; f++)
            #pragma unroll
            for (int g = 0; g < 4; g++)
                acc[f][g] = MFMA16(a[f], b[g], acc[f][g]);
    }

    #pragma unroll
    for (int f = 0; f < 4; f++) {
        const int mbase = m0 + f * 16 + r0;
        #pragma unroll
        for (int g = 0; g < 4; g++) {
            const int gcol = n0 + g * 16 + l15;
            *(f16x4*)(XgT + (size_t)gcol * MCH + mbase) =
                __builtin_convertvector(acc[f][g], f16x4);
        }
    }
}

// ---------------------------------------------------------------------------
// Atomic-free distributed barrier (64 blocks/group).
// arrive: drain stores, block-sync, one relaxed agent STORE of this block's
//         epoch to its own 64B-spaced word (no RMW -> no L3 serialization).
// wait:   lanes 0..63 each poll ONE producer's word in parallel (64 distinct
//         lines, one L3 RT per round); lane exits when its word >= target.
// Post-last-arrival chain: store flight + one poll round (~1-1.5 us), vs
// 64 same-line fetch_adds (~3-5 us serialized) for the counter variants.
// ---------------------------------------------------------------------------
__device__ __forceinline__ void g_arrive(unsigned* myword, unsigned val) {
    asm volatile("s_waitcnt vmcnt(0) lgkmcnt(0)" ::: "memory");
    __syncthreads();
    if (threadIdx.x == 0)
        __hip_atomic_store(myword, val, __ATOMIC_RELAXED, __HIP_MEMORY_SCOPE_AGENT);
}
__device__ __forceinline__ void g_wait(const unsigned* arr, unsigned tgt) {
    if (threadIdx.x < 64) {
        const unsigned* p = arr + threadIdx.x * 16;
        while (__hip_atomic_load(p, __ATOMIC_RELAXED, __HIP_MEMORY_SCOPE_AGENT) < tgt)
            __builtin_amdgcn_s_sleep(1);
    }
    __syncthreads();
}

// ---------------------------------------------------------------------------
// Persistent cooperative LSTM segment — WEIGHTS-STATIONARY (round 4, proven)
// + atomic-free barrier (this round's single change).
// Each block parks its 64 Whh gate-rows swizzled in LDS (131072 B); per step
// only h (32 KB/block) moves; cell MFMAs are LDS-fed. Decode: Whh from LDS,
// Wih/Wout streamed; softlse is 2-pass over cached global y.
// gbuf aliases the A-tile (resynced).
// ---------------------------------------------------------------------------
__global__ __launch_bounds__(256, 1) void lstm_coop(
    const ushort* __restrict__ Wih, const ushort* __restrict__ Whh,
    const ushort* __restrict__ Wout, const _Float16* __restrict__ XgT,
    ushort* __restrict__ Hbase, float* __restrict__ Ybase,
    unsigned* __restrict__ bar,
    const float* __restrict__ b_ih, const float* __restrict__ b_hh,
    const float* __restrict__ b_out, float* __restrict__ cbuf,
    float* __restrict__ out, int t0, int nsteps, int dodec, unsigned ep0)
{
    __shared__ ushort WB[64 * 1024];   // 131072 B swizzled Whh slice (resident)
    __shared__ ushort AT[16 * 1024];   //  32768 B swizzled A tile (h, then x)
    float* gbuf = (float*)AT;          // alias: cross-wave gate/proj exchange

    const int blk  = blockIdx.x;
    const int bg   = blk >> 6, ug = blk & 63;
    const int tid  = threadIdx.x;
    const int wave = tid >> 6, lane = tid & 63;
    const int l15  = lane & 15, q8 = (lane >> 4) * 8, r0 = (lane >> 4) * 4;
    const int b    = tid >> 4, u = tid & 15;

    unsigned* arr    = bar + bg * 1024;    // this group's 64 arrival words
    unsigned* myword = arr + ug * 16;      // 64B apart
    unsigned ep = ep0;                     // phases completed so far

    const int gi = ug * 16 + u;
    const float bs0 = b_ih[gi]        + b_hh[gi];
    const float bs1 = b_ih[1024 + gi] + b_hh[1024 + gi];
    const float bs2 = b_ih[2048 + gi] + b_hh[2048 + gi];
    const float bs3 = b_ih[3072 + gi] + b_hh[3072 + gi];
    const int cidx = ((bg * 16 + b) << 10) + gi;
    float c_reg = cbuf[cidx];

    // park Whh slice in LDS (once per launch): rows rr = gate*16 + j
    for (int it = 0; it < 32; it++) {
        int idx = it * 256 + tid;          // granule id, 8192 total
        int row = idx >> 7, g = idx & 127;
        const ushort* src = Whh
            + (((size_t)((row >> 4) * 1024 + ug * 16 + (row & 15))) << 10) + g * 8;
        *(short8*)&WB[(row << 10) + ((g ^ (row & 7)) << 3)] = *(const short8*)src;
    }
    __syncthreads();

    const ushort* wip = Wih + (((size_t)(wave * 1024 + ug * 16 + l15)) << 10) + q8;
    const ushort* wop = Wout + (((size_t)(ug * 16 + l15)) << 10) + wave * 256 + q8;
    const _Float16* xgp = XgT + (size_t)(wave * 1024 + ug * 16 + l15) * MCH
                              + bg * 16 + r0;
    const int wrow = wave * 16 + l15;  // this lane's WB row

    auto hbuf = [&](int t) -> ushort* {
        return Hbase + (size_t)(NHBUF - 1 - t) * NE;
    };

    // stage 16x1024 bf16 global slice -> swizzled AT
    auto stage_swz = [&](const ushort* __restrict__ src) {
        short8 t[8];
        #pragma unroll
        for (int i = 0; i < 8; i++) {
            int idx = i * 256 + tid;
            t[i] = *(const short8*)(src + ((size_t)(idx >> 7) << 10) + (idx & 127) * 8);
        }
        #pragma unroll
        for (int i = 0; i < 8; i++) {
            int idx = i * 256 + tid;
            int row = idx >> 7, g = idx & 127;
            *(short8*)&AT[(row << 10) + ((g ^ (row & 7)) << 3)] = t[i];
        }
    };

    auto gwrite = [&](f32x4 acc) {      // caller must __syncthreads() before
        #pragma unroll
        for (int r = 0; r < 4; r++)
            gbuf[(r0 + r) * 68 + wave * 16 + l15] = acc[r];
    };

    auto pointwise = [&](ushort* hnxt, bool fin) {
        float ig = gbuf[b * 68 + u]      + bs0;
        float fg = gbuf[b * 68 + 16 + u] + bs1;
        float gg = gbuf[b * 68 + 32 + u] + bs2;
        float og = gbuf[b * 68 + 48 + u] + bs3;
        float si = 1.f / (1.f + expf(-ig));
        float sf = 1.f / (1.f + expf(-fg));
        float so = 1.f / (1.f + expf(-og));
        float tg = tanhf(gg);
        float cn = sf * c_reg + si * tg;
        c_reg = cn;
        float hn = so * tanhf(cn);
        ushort hb16 = bf16_rne(hn);
        unsigned hi = (unsigned)(ushort)__shfl_down((int)hb16, 1);
        if ((u & 1) == 0)
            cstore32((void*)(hnxt + cidx), (unsigned)hb16 | (hi << 16));
        if (fin) {
            out[(size_t)TOUT * NE + cidx]       = hn;
            out[(size_t)(TOUT + 1) * NE + cidx] = cn;
        }
    };

    auto proj_step = [&](const ushort* hcur, float* ydst) {
        stage_swz(hcur + ((size_t)(bg * 16) << 10));
        __syncthreads();
        f32x4 ac = {0.f, 0.f, 0.f, 0.f};
        #pragma unroll
        for (int kk = 0; kk < 256; kk += 32)
            ac = MFMA16(*(const short8*)(AT + swz(l15, wave * 256 + q8 + kk)),
                        *(const short8*)(wop + kk), ac);
        __syncthreads();               // all AT reads done (gbuf aliases AT)
        #pragma unroll
        for (int r = 0; r < 4; r++)
            gbuf[wave * 256 + (r0 + r) * 16 + l15] = ac[r];
        __syncthreads();
        float vv = gbuf[b * 16 + u] + gbuf[256 + b * 16 + u]
                 + gbuf[512 + b * 16 + u] + gbuf[768 + b * 16 + u]
                 + b_out[ug * 16 + u];
        cstore32(ydst + (size_t)(bg * 16 + b) * 1024 + ug * 16 + u,
                 __float_as_uint(vv));
    };

    // 2-pass distributed log-softmax over cached global y; optional x-fill
    // into swizzled AT. Thread (b,u) owns row bg*16+b, cols {u*4 + s*64}.
    auto softlse = [&](const float* yb, float* outp, bool fill_at) {
        const float* yrow = yb + (size_t)(bg * 16 + b) * 1024 + u * 4;
        float mx = -3.4e38f;
        #pragma unroll
        for (int s = 0; s < 16; s++) {
            float4 v = *(const float4*)(yrow + s * 64);
            mx = fmaxf(mx, fmaxf(fmaxf(v.x, v.y), fmaxf(v.z, v.w)));
        }
        #pragma unroll
        for (int k = 1; k < 16; k <<= 1)
            mx = fmaxf(mx, __shfl_xor(mx, k, 16));
        float sm = 0.f;
        #pragma unroll
        for (int s = 0; s < 16; s++) {
            float4 v = *(const float4*)(yrow + s * 64);
            sm += expf(v.x - mx) + expf(v.y - mx)
                + expf(v.z - mx) + expf(v.w - mx);
        }
        #pragma unroll
        for (int k = 1; k < 16; k <<= 1)
            sm += __shfl_xor(sm, k, 16);
        const float lse = mx + logf(sm);
        if ((u >> 2) == (ug & 3)) {        // these lanes hold cols ug*16..+15
            float4 v = *(const float4*)(yrow + (ug >> 2) * 64);
            v.x -= lse; v.y -= lse; v.z -= lse; v.w -= lse;
            *(float4*)(outp + (size_t)(bg * 16 + b) * 1024 + ug * 16 + (u & 3) * 4) = v;
        }
        if (fill_at) {
            #pragma unroll
            for (int s = 0; s < 16; s++) {
                float4 v = *(const float4*)(yrow + s * 64);
                ushort4 w4;
                w4.x = bf16_rne(v.x - lse); w4.y = bf16_rne(v.y - lse);
                w4.z = bf16_rne(v.z - lse); w4.w = bf16_rne(v.w - lse);
                int col = u * 4 + s * 64;
                *(ushort4*)&AT[swz(b, col)] = w4;
            }
        }
    };

    // ================= encode segment: 1 barrier/step =================
    for (int s = 0; s < nsteps; s++) {
        const int t = t0 + s;
        f16x4 xg4 = *(const f16x4*)(xgp + (size_t)s * 64);   // indep of h(t)
        g_wait(arr, ep);                   // h(t) visible
        stage_swz(hbuf(t) + ((size_t)(bg * 16) << 10));
        __syncthreads();
        f32x4 a0 = __builtin_convertvector(xg4, f32x4);
        f32x4 a1 = {0.f, 0.f, 0.f, 0.f};
        #pragma unroll 8
        for (int kk = 0; kk < 512; kk += 32)
            a0 = MFMA16(*(const short8*)(AT + swz(l15, kk + q8)),
                        *(const short8*)(WB + swz(wrow, kk + q8)), a0);
        #pragma unroll 8
        for (int kk = 512; kk < 1024; kk += 32)
            a1 = MFMA16(*(const short8*)(AT + swz(l15, kk + q8)),
                        *(const short8*)(WB + swz(wrow, kk + q8)), a1);
        __syncthreads();                   // AT reads done (gbuf aliases AT)
        gwrite(a0 + a1);
        __syncthreads();
        pointwise(hbuf(t + 1), false);
        g_arrive(myword, ep + 1); ep++;    // publish h(t+1)
    }

    if (!dodec) {
        cbuf[cidx] = c_reg;   // spill recurrent c for the next segment
        return;
    }

    // ================= out0 =================
    g_wait(arr, ep);                       // h(SEQ) visible
    proj_step(hbuf(SEQ), Ybase);           // y slot 0
    g_arrive(myword, ep + 1); ep++;

    // ================= decode: 31 steps, 2 barriers each =================
    for (int d = 1; d < TOUT; d++) {
        // ---- cell(d): h-GEMM (LDS weights) in the y-wait shadow ----
        stage_swz(hbuf(SEQ + d - 1) + ((size_t)(bg * 16) << 10));
        __syncthreads();
        f32x4 a0 = {0.f,0.f,0.f,0.f}, a1 = {0.f,0.f,0.f,0.f};
        #pragma unroll 8
        for (int kk = 0; kk < 512; kk += 32)
            a0 = MFMA16(*(const short8*)(AT + swz(l15, kk + q8)),
                        *(const short8*)(WB + swz(wrow, kk + q8)), a0);
        #pragma unroll 8
        for (int kk = 512; kk < 1024; kk += 32)
            a1 = MFMA16(*(const short8*)(AT + swz(l15, kk + q8)),
                        *(const short8*)(WB + swz(wrow, kk + q8)), a1);
        g_wait(arr, ep);                   // y(d-1) visible (syncthreads inside)
        softlse(Ybase + (size_t)(d - 1) * NE, out + (size_t)(d - 1) * NE, true);
        __syncthreads();                   // AT now holds x(d-1)
        #pragma unroll 8
        for (int kk = 0; kk < 512; kk += 32)
            a0 = MFMA16(*(const short8*)(AT + swz(l15, kk + q8)),
                        *(const short8*)(wip + kk), a0);
        #pragma unroll 8
        for (int kk = 512; kk < 1024; kk += 32)
            a1 = MFMA16(*(const short8*)(AT + swz(l15, kk + q8)),
                        *(const short8*)(wip + kk), a1);
        __syncthreads();                   // AT reads done (gbuf aliases AT)
        gwrite(a0 + a1);
        __syncthreads();
        pointwise(hbuf(SEQ + d), d == TOUT - 1);
        g_arrive(myword, ep + 1); ep++;    // publish h(SEQ+d)

        // ---- proj(d) ----
        g_wait(arr, ep);                   // h(SEQ+d) visible
        proj_step(hbuf(SEQ + d), Ybase + (size_t)d * NE);
        g_arrive(myword, ep + 1); ep++;    // publish y(d)
    }

    // ================= epilogue: out[31] = y(31) - lse =================
    g_wait(arr, ep);                       // y(31) visible
    softlse(Ybase + (size_t)(TOUT - 1) * NE, out + (size_t)(TOUT - 1) * NE, false);
}

// ---------------------------------------------------------------------------
extern "C" void kernel_launch(void* const* d_in, const int* in_sizes, int n_in,
                              void* d_out, int out_size, void* d_ws, size_t ws_size,
                              hipStream_t stream)
{
    const float* input = (const float*)d_in[0];   // [128,64,1024]
    const float* h0    = (const float*)d_in[1];
    const float* c0    = (const float*)d_in[2];
    const float* W_ih  = (const float*)d_in[3];   // [4096,1024]
    const float* W_hh  = (const float*)d_in[4];
    const float* b_ih  = (const float*)d_in[5];
    const float* b_hh  = (const float*)d_in[6];
    const float* W_out = (const float*)d_in[7];   // [1024,1024]
    const float* b_out = (const float*)d_in[8];
    float* out = (float*)d_out;                   // [32,64,1024] + h + c

    char* w = (char*)d_ws;                                    // bytes
    ushort*    Whh_bf = (ushort*)   (w + 0);                  //  8,388,608
    ushort*    Wih_bf = (ushort*)   (w + 8388608);            //  8,388,608
    ushort*    Wout_bf= (ushort*)   (w + 16777216);           //  2,097,152
    _Float16*  XgT    = (_Float16*) (w + 18874368);           // 16,777,216
    ushort*    Xbc    = (ushort*)   (w + 35651584);           //  4,194,304
    ushort*    Hbase  = (ushort*)   (w + 39845888);           // 20,971,520
    float*     Ybase  = (float*)    (w + 60817408);           //  8,388,608 (32 slots)
    float*     cbuf   = (float*)    (w + 69206016);           //    262,144
    unsigned*  bar    = (unsigned*) (w + 69468160);           //     16,384
    // total ~69.5 MB (proven budget: 86.7 MB)

    cvt_bf16<<<dim3(4096), dim3(256), 0, stream>>>(W_ih,  Wih_bf,  NG * HD);
    cvt_bf16<<<dim3(4096), dim3(256), 0, stream>>>(W_hh,  Whh_bf,  NG * HD);
    cvt_bf16<<<dim3(1024), dim3(256), 0, stream>>>(W_out, Wout_bf, HD * HD);
    // hbuf(0) = Hbase + (NHBUF-1)*NE
    prep<<<dim3(256), dim3(256), 0, stream>>>(
        h0, c0, Hbase + (size_t)(NHBUF - 1) * NE, cbuf, bar);

    for (int ch = 0; ch < SEQ / CHS; ch++) {
        cvt_bf16<<<dim3(2048), dim3(256), 0, stream>>>(
            input + (size_t)ch * CHS * NE, Xbc, CHS * NE);
        gemm_xgt<<<dim3(32, 16), dim3(256), 0, stream>>>(Xbc, Wih_bf, XgT);

        const ushort* a0 = Wih_bf;  const ushort* a1 = Whh_bf;
        const ushort* a2 = Wout_bf; const _Float16* a3 = XgT;
        ushort* a4 = Hbase; float* a5 = Ybase; unsigned* a6 = bar;
        const float* a7 = b_ih; const float* a8 = b_hh; const float* a9 = b_out;
        float* a10 = cbuf; float* a11 = out;
        int t0 = ch * CHS, ns = CHS, dodec = (ch == SEQ / CHS - 1) ? 1 : 0;
        unsigned ep0 = (unsigned)(ch * CHS);   // phases completed in prior chunks
        void* args[] = {&a0, &a1, &a2, &a3, &a4, &a5, &a6, &a7,
                        &a8, &a9, &a10, &a11, &t0, &ns, &dodec, &ep0};
        hipLaunchCooperativeKernel((const void*)lstm_coop, dim3(256), dim3(256),
                                   args, 0, stream);
    }
}